// Round 1
// baseline (27736.652 us; speedup 1.0000x reference)
//
#include <hip/hip_runtime.h>
#include <hip/hip_fp16.h>

// ---------------------------------------------------------------------------
// 2-layer tanh RNN, B=256, T=512, H=512, D=64, + FC(512->1).
// Plan:
//   prep:   bias sums, fp16 packs of W_ih0/W_ih1, register/LDS-layout packs of W_hh0/W_hh1
//   proj0:  P[b,t,:] = x[b,t,:] @ W_ih0^T + (b_ih0+b_hh0)          (MFMA f16, K=64)
//   rec0:   per-CU weight-stationary recurrence, writes h1 in place over P
//   proj1:  P[b,t,:] = h1[b,t,:] @ W_ih1^T + (b_ih1+b_hh1)         (MFMA f16, K=512, in-place)
//   rec1:   recurrence + final FC -> d_out[256]
// Recurrence kernel: 256 WGs (1 batch chain each), 256 threads (4 waves, 1 wave/SIMD,
// __launch_bounds__(256,1) -> up to 512 VGPRs). Thread owns rows 2t,2t+1 of W_hh:
// row A fully in regs (256 VGPRs), row B k<320 in regs (160 VGPRs), k in [320,512)
// in LDS (96 KB). h double-buffered in LDS (fp16), one barrier per step.
// ---------------------------------------------------------------------------

typedef _Float16 h2 __attribute__((ext_vector_type(2)));
typedef _Float16 h8 __attribute__((ext_vector_type(8)));
typedef float    f4 __attribute__((ext_vector_type(4)));

#define HID   512
#define TSEQ  512
#define NBATCH 256
#define NLDSG 48          // uint2 (4-half) groups per thread in LDS: k in [320,512)

#if defined(__has_builtin)
#if __has_builtin(__builtin_amdgcn_fdot2)
#define HAVE_FDOT2 1
#endif
#endif

#ifdef HAVE_FDOT2
#define FDOT2(a, b, c) __builtin_amdgcn_fdot2((a), (b), (c), false)
#else
static __device__ __forceinline__ float FDOT2(h2 a, h2 b, float c) {
  return c + (float)a[0] * (float)b[0] + (float)a[1] * (float)b[1];
}
#endif

#define HP(v, i) __builtin_shufflevector((v), (v), 2 * (i), 2 * (i) + 1)

// ---------------- workspace layout (bytes) ----------------
static const size_t OFF_P   = 0;                         // [131072][512] fp16   134217728
static const size_t OFF_B0  = 134217728;                 // W_ih0 fp16 [512][64]     65536
static const size_t OFF_B1  = OFF_B0 + 65536;            // W_ih1 fp16 [512][512]   524288
static const size_t OFF_W0A = OFF_B1 + 524288;           // 64*256*16               262144
static const size_t OFF_W0B = OFF_W0A + 262144;          // 40*256*16               163840
static const size_t OFF_W0L = OFF_W0B + 163840;          // 48*256*8                 98304
static const size_t OFF_W1A = OFF_W0L + 98304;
static const size_t OFF_W1B = OFF_W1A + 262144;
static const size_t OFF_W1L = OFF_W1B + 163840;
static const size_t OFF_BS0 = OFF_W1L + 98304;           // bias0 f32 [512]
static const size_t OFF_BS1 = OFF_BS0 + 2048;            // bias1 f32 [512]

// ---------------- prep kernels ----------------
__global__ void bias_kernel(const float* __restrict__ bih0, const float* __restrict__ bhh0,
                            const float* __restrict__ bih1, const float* __restrict__ bhh1,
                            float* __restrict__ bias0, float* __restrict__ bias1) {
  int i = threadIdx.x;   // block 512
  bias0[i] = bih0[i] + bhh0[i];
  bias1[i] = bih1[i] + bhh1[i];
}

__global__ void cvt_half_kernel(const float* __restrict__ in, _Float16* __restrict__ outp, int n) {
  int i = blockIdx.x * 256 + threadIdx.x;
  if (i < n) outp[i] = (_Float16)in[i];
}

// Pack W_hh (fp32 [512][512]) into the recurrence kernel's load layouts.
// WA[c][tid] (c<64):  8 halfs = W[2*tid][8c..8c+8)
// WB[c][tid] (c<40):  8 halfs = W[2*tid+1][8c..8c+8)
// WL[g][tid] (g<48):  4 halfs = W[2*tid+1][320+4g..320+4g+4)
__global__ void pack_whh_kernel(const float* __restrict__ W, f4* __restrict__ WA,
                                f4* __restrict__ WB, uint2* __restrict__ WL) {
  int tid = threadIdx.x;
  int blk = blockIdx.x;
  if (blk < 64) {
    int c = blk;
    const float* src = W + (size_t)(2 * tid) * HID + 8 * c;
    h8 v;
#pragma unroll
    for (int i = 0; i < 8; ++i) v[i] = (_Float16)src[i];
    WA[c * 256 + tid] = __builtin_bit_cast(f4, v);
  } else if (blk < 104) {
    int c = blk - 64;
    const float* src = W + (size_t)(2 * tid + 1) * HID + 8 * c;
    h8 v;
#pragma unroll
    for (int i = 0; i < 8; ++i) v[i] = (_Float16)src[i];
    WB[c * 256 + tid] = __builtin_bit_cast(f4, v);
  } else {
    int g = blk - 104;
    const float* src = W + (size_t)(2 * tid + 1) * HID + 320 + 4 * g;
    h2 p0, p1;
    p0[0] = (_Float16)src[0]; p0[1] = (_Float16)src[1];
    p1[0] = (_Float16)src[2]; p1[1] = (_Float16)src[3];
    uint2 u;
    u.x = __builtin_bit_cast(unsigned, p0);
    u.y = __builtin_bit_cast(unsigned, p1);
    WL[g * 256 + tid] = u;
  }
}

// ---------------- projection GEMM (MFMA f16) ----------------
// C[m][n] = sum_k A[m][k]*Bw[n][k] + bias[n];  M = gridDim*64, N = 512.
// WG: 64 M-rows x full N=512 (so in-place A==C is race-free: only this WG's
// threads read those rows, and all reads precede the epilogue stores).
template <typename AT, int K>
__global__ __launch_bounds__(256, 2) void proj_kernel(const AT* A, const _Float16* __restrict__ Bw,
                                                      _Float16* C, const float* __restrict__ bias) {
  __shared__ _Float16 At[64][40];    // +8 pad -> 2-way max (free)
  __shared__ _Float16 Bt[512][40];
  const int tid = threadIdx.x;
  const int m0 = blockIdx.x * 64;
  const int wv = tid >> 6;
  const int l = tid & 63;
  const int n0 = wv * 128;
  const int lm = l & 15;
  const int lq = l >> 4;

  f4 acc[4][8];
#pragma unroll
  for (int i = 0; i < 4; ++i)
#pragma unroll
    for (int j = 0; j < 8; ++j) acc[i][j] = (f4){0.f, 0.f, 0.f, 0.f};

  const int arow = tid >> 2;        // 0..63
  const int kq = (tid & 3) * 8;     // 0,8,16,24

  for (int k0 = 0; k0 < K; k0 += 32) {
    // stage A tile (64 x 32)
    if (sizeof(AT) == 4) {
      const float* ap = (const float*)A + (size_t)(m0 + arow) * K + k0 + kq;
      h8 v;
#pragma unroll
      for (int i = 0; i < 8; ++i) v[i] = (_Float16)ap[i];
      *(h8*)&At[arow][kq] = v;
    } else {
      *(h8*)&At[arow][kq] = *(const h8*)((const _Float16*)A + (size_t)(m0 + arow) * K + k0 + kq);
    }
    // stage B slab (512 x 32)
#pragma unroll
    for (int rr = 0; rr < 8; ++rr) {
      int rrow = arow + rr * 64;
      *(h8*)&Bt[rrow][kq] = *(const h8*)(Bw + (size_t)rrow * K + k0 + kq);
    }
    __syncthreads();
    h8 af[4];
#pragma unroll
    for (int mm = 0; mm < 4; ++mm) af[mm] = *(const h8*)&At[mm * 16 + lm][lq * 8];
#pragma unroll
    for (int nn = 0; nn < 8; ++nn) {
      h8 bf = *(const h8*)&Bt[n0 + nn * 16 + lm][lq * 8];
#pragma unroll
      for (int mm = 0; mm < 4; ++mm)
        acc[mm][nn] = __builtin_amdgcn_mfma_f32_16x16x32_f16(af[mm], bf, acc[mm][nn], 0, 0, 0);
    }
    __syncthreads();
  }
  // epilogue: D[row = lq*4+r][col = lm] per 16x16 frag
#pragma unroll
  for (int nn = 0; nn < 8; ++nn) {
    int col = n0 + nn * 16 + lm;
    float bv = bias[col];
#pragma unroll
    for (int mm = 0; mm < 4; ++mm) {
#pragma unroll
      for (int r = 0; r < 4; ++r) {
        int row = m0 + mm * 16 + lq * 4 + r;
        C[(size_t)row * HID + col] = (_Float16)(acc[mm][nn][r] + bv);
      }
    }
  }
}

// ---------------- recurrence kernel ----------------
template <bool WRITE_H, bool DO_FC>
__global__ __launch_bounds__(256, 1) void rec_kernel(
    const _Float16* __restrict__ P, _Float16* __restrict__ Pout,
    const f4* __restrict__ WA, const f4* __restrict__ WB, const uint2* __restrict__ WL,
    const float* __restrict__ Wfc, const float* __restrict__ bfc, float* __restrict__ out) {
  __shared__ __align__(16) _Float16 hbuf[2][HID];   // 2 KB
  __shared__ uint2 Wl[NLDSG][256];                  // 96 KB
  __shared__ float red[4];
  const int tid = threadIdx.x;
  const int b = blockIdx.x;

  // load weight registers (coalesced 16B chunks)
  f4 wa[64];
#pragma unroll
  for (int c = 0; c < 64; ++c) wa[c] = WA[c * 256 + tid];
  f4 wb[40];
#pragma unroll
  for (int c = 0; c < 40; ++c) wb[c] = WB[c * 256 + tid];
#pragma unroll
  for (int g = 0; g < NLDSG; ++g) Wl[g][tid] = WL[g * 256 + tid];

  ((unsigned*)hbuf)[tid] = 0u;          // h0 = 0 (covers both buffers)
  ((unsigned*)hbuf)[256 + tid] = 0u;
  __syncthreads();

  const _Float16* prow = P + (size_t)b * TSEQ * HID;
  unsigned xp_cur = *(const unsigned*)(prow + 2 * tid);
  float lh0 = 0.f, lh1 = 0.f;

#pragma unroll 1
  for (int t = 0; t < TSEQ; ++t) {
    int tn = (t + 1 < TSEQ) ? t + 1 : t;
    unsigned xp_next = *(const unsigned*)(prow + (size_t)tn * HID + 2 * tid);
    const _Float16* h = hbuf[t & 1];
    float a0 = 0.f, a1 = 0.f, a2 = 0.f, a3 = 0.f;
#pragma unroll
    for (int c = 0; c < 64; ++c) {
      h8 hc = *(const h8*)(h + 8 * c);
      {
        h8 wac = __builtin_bit_cast(h8, wa[c]);
        a0 = FDOT2(HP(wac, 0), HP(hc, 0), a0);
        a1 = FDOT2(HP(wac, 1), HP(hc, 1), a1);
        a0 = FDOT2(HP(wac, 2), HP(hc, 2), a0);
        a1 = FDOT2(HP(wac, 3), HP(hc, 3), a1);
      }
      if (c < 40) {
        h8 wbc = __builtin_bit_cast(h8, wb[c]);
        a2 = FDOT2(HP(wbc, 0), HP(hc, 0), a2);
        a3 = FDOT2(HP(wbc, 1), HP(hc, 1), a3);
        a2 = FDOT2(HP(wbc, 2), HP(hc, 2), a2);
        a3 = FDOT2(HP(wbc, 3), HP(hc, 3), a3);
      } else {
        uint2 u0 = Wl[2 * c - 80][tid];
        uint2 u1 = Wl[2 * c - 79][tid];
        a2 = FDOT2(__builtin_bit_cast(h2, u0.x), HP(hc, 0), a2);
        a3 = FDOT2(__builtin_bit_cast(h2, u0.y), HP(hc, 1), a3);
        a2 = FDOT2(__builtin_bit_cast(h2, u1.x), HP(hc, 2), a2);
        a3 = FDOT2(__builtin_bit_cast(h2, u1.y), HP(hc, 3), a3);
      }
    }
    h2 xph = __builtin_bit_cast(h2, xp_cur);
    float v0 = tanhf(a0 + a1 + (float)xph[0]);
    float v1 = tanhf(a2 + a3 + (float)xph[1]);
    lh0 = v0;
    lh1 = v1;
    h2 hw;
    hw[0] = (_Float16)v0;
    hw[1] = (_Float16)v1;
    *(h2*)(&hbuf[(t + 1) & 1][2 * tid]) = hw;
    if (WRITE_H) {
      _Float16* pw = Pout + (size_t)b * TSEQ * HID + (size_t)t * HID + 2 * tid;
      *(h2*)pw = hw;
    }
    __syncthreads();
    xp_cur = xp_next;
  }

  if (DO_FC) {
    float fc = lh0 * Wfc[2 * tid] + lh1 * Wfc[2 * tid + 1];
#pragma unroll
    for (int off = 32; off; off >>= 1) fc += __shfl_down(fc, off, 64);
    if ((tid & 63) == 0) red[tid >> 6] = fc;
    __syncthreads();
    if (tid == 0) out[b] = red[0] + red[1] + red[2] + red[3] + bfc[0];
  }
}

// ---------------- launcher ----------------
extern "C" void kernel_launch(void* const* d_in, const int* in_sizes, int n_in,
                              void* d_out, int out_size, void* d_ws, size_t ws_size,
                              hipStream_t stream) {
  const float* x    = (const float*)d_in[0];
  const float* Wih0 = (const float*)d_in[1];
  const float* Whh0 = (const float*)d_in[2];
  const float* bih0 = (const float*)d_in[3];
  const float* bhh0 = (const float*)d_in[4];
  const float* Wih1 = (const float*)d_in[5];
  const float* Whh1 = (const float*)d_in[6];
  const float* bih1 = (const float*)d_in[7];
  const float* bhh1 = (const float*)d_in[8];
  const float* Wfc  = (const float*)d_in[9];
  const float* bfc  = (const float*)d_in[10];
  float* out = (float*)d_out;
  char* ws = (char*)d_ws;

  _Float16* P    = (_Float16*)(ws + OFF_P);
  _Float16* B0   = (_Float16*)(ws + OFF_B0);
  _Float16* B1   = (_Float16*)(ws + OFF_B1);
  f4*    W0A  = (f4*)(ws + OFF_W0A);
  f4*    W0B  = (f4*)(ws + OFF_W0B);
  uint2* W0L  = (uint2*)(ws + OFF_W0L);
  f4*    W1A  = (f4*)(ws + OFF_W1A);
  f4*    W1B  = (f4*)(ws + OFF_W1B);
  uint2* W1L  = (uint2*)(ws + OFF_W1L);
  float* bias0 = (float*)(ws + OFF_BS0);
  float* bias1 = (float*)(ws + OFF_BS1);

  bias_kernel<<<1, 512, 0, stream>>>(bih0, bhh0, bih1, bhh1, bias0, bias1);
  cvt_half_kernel<<<128, 256, 0, stream>>>(Wih0, B0, 512 * 64);
  cvt_half_kernel<<<1024, 256, 0, stream>>>(Wih1, B1, 512 * 512);
  pack_whh_kernel<<<152, 256, 0, stream>>>(Whh0, W0A, W0B, W0L);
  pack_whh_kernel<<<152, 256, 0, stream>>>(Whh1, W1A, W1B, W1L);

  // proj0: xp0 = x @ W_ih0^T + bias0   (M = 256*512 rows)
  proj_kernel<float, 64><<<2048, 256, 0, stream>>>(x, B0, P, bias0);
  // rec0: h1 written in place over P
  rec_kernel<true, false><<<NBATCH, 256, 0, stream>>>(P, P, W0A, W0B, W0L, nullptr, nullptr, nullptr);
  // proj1: xp1 = h1 @ W_ih1^T + bias1, in place
  proj_kernel<_Float16, 512><<<2048, 256, 0, stream>>>(P, B1, P, bias1);
  // rec1: final hidden -> FC -> out
  rec_kernel<false, true><<<NBATCH, 256, 0, stream>>>(P, nullptr, W1A, W1B, W1L, Wfc, bfc, out);
}

// Round 2
// 2674.169 us; speedup vs baseline: 10.3721x; 10.3721x over previous
//
#include <hip/hip_runtime.h>
#include <hip/hip_fp16.h>

// ---------------------------------------------------------------------------
// 2-layer tanh RNN, B=256, T=512, H=512, D=64, + FC(512->1).
//   proj0:  P[b,t,:] = x[b,t,:] @ W_ih0^T + (b_ih0+b_hh0)     (MFMA f16, K=64)
//   rec0:   per-CU recurrence via M=1 MFMA, writes h1 in place over P
//   proj1:  P[b,t,:] = h1[b,t,:] @ W_ih1^T + (b_ih1+b_hh1)    (in-place)
//   rec1:   recurrence + final FC -> d_out[256]
// rec engine: one chain per CU, 256 threads (4 waves, 1 wave/SIMD).
// W_hh held as MFMA B-fragments: NREG=100 frags/wave in registers (AGPR-
// reachable because they are MFMA operands; round-1 fdot2 design spilled to
// scratch at 19 GB HBM traffic since only 256 arch VGPRs are addressable),
// NLDS=28 frags/wave in LDS (112 KB re-read per step, overlapped with MFMA).
// ---------------------------------------------------------------------------

typedef _Float16 h2 __attribute__((ext_vector_type(2)));
typedef _Float16 h8 __attribute__((ext_vector_type(8)));
typedef float    f4 __attribute__((ext_vector_type(4)));

#define HID   512
#define TSEQ  512
#define NB    256
#define NREG  100   // B-frags per wave in registers
#define NLDS  28    // B-frags per wave in LDS

// per k-step (kk), how many of the 8 n-group frags come from LDS
__host__ __device__ constexpr int nl_of(int kk) { return (kk % 4 == 0) ? 1 : 2; }

// ---------------- workspace layout (bytes) ----------------
static const size_t OFF_P   = 0;                       // [131072][512] fp16  134217728
static const size_t OFF_B0  = 134217728;               // W_ih0 fp16 [512][64]    65536
static const size_t OFF_B1  = OFF_B0 + 65536;          // W_ih1 fp16 [512][512]  524288
static const size_t OFF_R0  = OFF_B1 + 524288;         // BregP layer0 4*100*64*16 = 409600
static const size_t OFF_L0  = OFF_R0 + 409600;         // BldsP layer0 4*28*64*16 = 114688
static const size_t OFF_R1  = OFF_L0 + 114688;
static const size_t OFF_L1  = OFF_R1 + 409600;
static const size_t OFF_BS0 = OFF_L1 + 114688;         // bias0 f32 [512]
static const size_t OFF_BS1 = OFF_BS0 + 2048;          // bias1 f32 [512]

// ---------------- prep kernels ----------------
__global__ void bias_kernel(const float* __restrict__ bih0, const float* __restrict__ bhh0,
                            const float* __restrict__ bih1, const float* __restrict__ bhh1,
                            float* __restrict__ bias0, float* __restrict__ bias1) {
  int i = threadIdx.x;  // block 512
  bias0[i] = bih0[i] + bhh0[i];
  bias1[i] = bih1[i] + bhh1[i];
}

__global__ void cvt_half_kernel(const float* __restrict__ in, _Float16* __restrict__ outp, int n) {
  int i = blockIdx.x * 256 + threadIdx.x;
  if (i < n) outp[i] = (_Float16)in[i];
}

// Pack W_hh (fp32 [512][512]) into MFMA B-fragment order.
// Fragment for (wave w, n-group g, k-step kk), lane l:
//   8 halfs = W[128w + 16g + (l&15)][kk*32 + (l>>4)*8 .. +8)
// Placed in BregP slot or BldsP slot per the rec kernel's k-loop issue order.
__global__ void pack_rec_kernel(const float* __restrict__ W, uint4* __restrict__ BregP,
                                uint4* __restrict__ BldsP) {
  int t = blockIdx.x * 256 + threadIdx.x;   // 32768 threads
  int l  = t & 63;
  int g  = (t >> 6) & 7;
  int kk = (t >> 9) & 15;
  int w  = (t >> 13) & 3;
  int nl = nl_of(kk);
  bool lds = (g >= 8 - nl);
  int slot;
  if (!lds) {
    int R = 0;
    for (int j = 0; j < kk; ++j) R += 8 - nl_of(j);
    slot = R + g;
  } else {
    int L = 0;
    for (int j = 0; j < kk; ++j) L += nl_of(j);
    slot = L + (g - (8 - nl));
  }
  int n  = 128 * w + 16 * g + (l & 15);
  int k0 = kk * 32 + (l >> 4) * 8;
  const float* src = W + (size_t)n * HID + k0;
  h8 v;
#pragma unroll
  for (int i = 0; i < 8; ++i) v[i] = (_Float16)src[i];
  uint4 u = __builtin_bit_cast(uint4, v);
  if (lds) BldsP[(w * NLDS + slot) * 64 + l] = u;
  else     BregP[(w * NREG + slot) * 64 + l] = u;
}

// ---------------- projection GEMM (MFMA f16) ----------------
template <typename AT, int K>
__global__ __launch_bounds__(256, 2) void proj_kernel(const AT* A, const _Float16* __restrict__ Bw,
                                                      _Float16* C, const float* __restrict__ bias) {
  __shared__ _Float16 At[64][40];
  __shared__ _Float16 Bt[512][40];
  const int tid = threadIdx.x;
  const int m0 = blockIdx.x * 64;
  const int wv = tid >> 6;
  const int l = tid & 63;
  const int n0 = wv * 128;
  const int lm = l & 15;
  const int lq = l >> 4;

  f4 acc[4][8];
#pragma unroll
  for (int i = 0; i < 4; ++i)
#pragma unroll
    for (int j = 0; j < 8; ++j) acc[i][j] = (f4){0.f, 0.f, 0.f, 0.f};

  const int arow = tid >> 2;
  const int kq = (tid & 3) * 8;

  for (int k0 = 0; k0 < K; k0 += 32) {
    if (sizeof(AT) == 4) {
      const float* ap = (const float*)A + (size_t)(m0 + arow) * K + k0 + kq;
      h8 v;
#pragma unroll
      for (int i = 0; i < 8; ++i) v[i] = (_Float16)ap[i];
      *(h8*)&At[arow][kq] = v;
    } else {
      *(h8*)&At[arow][kq] = *(const h8*)((const _Float16*)A + (size_t)(m0 + arow) * K + k0 + kq);
    }
#pragma unroll
    for (int rr = 0; rr < 8; ++rr) {
      int rrow = arow + rr * 64;
      *(h8*)&Bt[rrow][kq] = *(const h8*)(Bw + (size_t)rrow * K + k0 + kq);
    }
    __syncthreads();
    h8 af[4];
#pragma unroll
    for (int mm = 0; mm < 4; ++mm) af[mm] = *(const h8*)&At[mm * 16 + lm][lq * 8];
#pragma unroll
    for (int nn = 0; nn < 8; ++nn) {
      h8 bf = *(const h8*)&Bt[n0 + nn * 16 + lm][lq * 8];
#pragma unroll
      for (int mm = 0; mm < 4; ++mm)
        acc[mm][nn] = __builtin_amdgcn_mfma_f32_16x16x32_f16(af[mm], bf, acc[mm][nn], 0, 0, 0);
    }
    __syncthreads();
  }
#pragma unroll
  for (int nn = 0; nn < 8; ++nn) {
    int col = n0 + nn * 16 + lm;
    float bv = bias[col];
#pragma unroll
    for (int mm = 0; mm < 4; ++mm) {
#pragma unroll
      for (int r = 0; r < 4; ++r) {
        int row = m0 + mm * 16 + lq * 4 + r;
        C[(size_t)row * HID + col] = (_Float16)(acc[mm][nn][r] + bv);
      }
    }
  }
}

// ---------------- recurrence kernel (M=1 MFMA) ----------------
template <bool WRITE_H, bool DO_FC>
__global__ __launch_bounds__(256, 1) void rec_kernel(
    const _Float16* __restrict__ P, _Float16* __restrict__ Pout,
    const uint4* __restrict__ BregP, const uint4* __restrict__ BldsP,
    const float* __restrict__ Wfc, const float* __restrict__ bfc, float* __restrict__ out) {
  __shared__ __align__(16) uint4 Blds[4 * NLDS * 64];   // 114688 B
  __shared__ __align__(16) _Float16 hbuf[HID];          // 1 KB
  __shared__ __align__(16) float hraw[HID];             // 2 KB
  __shared__ float red[4];
  const int tid = threadIdx.x;
  const int b = blockIdx.x;
  const int w = tid >> 6, l = tid & 63, lq = l >> 4;

  // load register-resident B fragments (MFMA operands -> AGPR-eligible)
  h8 breg[NREG];
#pragma unroll
  for (int i = 0; i < NREG; ++i)
    breg[i] = __builtin_bit_cast(h8, BregP[(w * NREG + i) * 64 + l]);
  // stage LDS-resident fragments
#pragma unroll
  for (int j = 0; j < NLDS; ++j)
    Blds[(w * NLDS + j) * 64 + l] = BldsP[(w * NLDS + j) * 64 + l];

  ((unsigned*)hbuf)[tid] = 0u;   // h0 = 0
  __syncthreads();

  const _Float16* prow = P + (size_t)b * TSEQ * HID;
  unsigned xp_cur = *(const unsigned*)(prow + 2 * tid);
  float lv0 = 0.f, lv1 = 0.f;

#pragma unroll 1
  for (int t = 0; t < TSEQ; ++t) {
    int tn = (t + 1 < TSEQ) ? t + 1 : t;
    unsigned xp_next = *(const unsigned*)(prow + (size_t)tn * HID + 2 * tid);

    f4 acc[8];
#pragma unroll
    for (int g = 0; g < 8; ++g) acc[g] = (f4){0.f, 0.f, 0.f, 0.f};

    int ri = 0, li = 0;
#pragma unroll
    for (int kk = 0; kk < 16; ++kk) {
      // A-frag: h replicated into all 16 rows (same addr per 16-lane quad -> broadcast)
      h8 a = *(const h8*)(hbuf + kk * 32 + lq * 8);
      const int nl = nl_of(kk);
#pragma unroll
      for (int g = 0; g < 8; ++g) {
        h8 bf;
        if (g < 8 - nl) bf = breg[ri++];
        else            bf = __builtin_bit_cast(h8, Blds[(w * NLDS + (li++)) * 64 + l]);
        acc[g] = __builtin_amdgcn_mfma_f32_16x16x32_f16(a, bf, acc[g], 0, 0, 0);
      }
    }

    // D row 0 (all rows identical since A rows replicated): lanes 0..15, reg 0
    if (l < 16) {
#pragma unroll
      for (int g = 0; g < 8; ++g) hraw[128 * w + 16 * g + l] = acc[g][0];
    }
    __syncthreads();

    float2 hr = *(const float2*)(hraw + 2 * tid);
    h2 xph = __builtin_bit_cast(h2, xp_cur);
    float v0 = tanhf(hr.x + (float)xph[0]);
    float v1 = tanhf(hr.y + (float)xph[1]);
    lv0 = v0; lv1 = v1;
    h2 hw; hw[0] = (_Float16)v0; hw[1] = (_Float16)v1;
    *(h2*)(hbuf + 2 * tid) = hw;
    if (WRITE_H)
      *(h2*)(Pout + (size_t)b * TSEQ * HID + (size_t)t * HID + 2 * tid) = hw;
    __syncthreads();
    xp_cur = xp_next;
  }

  if (DO_FC) {
    float fc = lv0 * Wfc[2 * tid] + lv1 * Wfc[2 * tid + 1];
#pragma unroll
    for (int off = 32; off; off >>= 1) fc += __shfl_down(fc, off, 64);
    if ((tid & 63) == 0) red[tid >> 6] = fc;
    __syncthreads();
    if (tid == 0) out[b] = red[0] + red[1] + red[2] + red[3] + bfc[0];
  }
}

// ---------------- launcher ----------------
extern "C" void kernel_launch(void* const* d_in, const int* in_sizes, int n_in,
                              void* d_out, int out_size, void* d_ws, size_t ws_size,
                              hipStream_t stream) {
  const float* x    = (const float*)d_in[0];
  const float* Wih0 = (const float*)d_in[1];
  const float* Whh0 = (const float*)d_in[2];
  const float* bih0 = (const float*)d_in[3];
  const float* bhh0 = (const float*)d_in[4];
  const float* Wih1 = (const float*)d_in[5];
  const float* Whh1 = (const float*)d_in[6];
  const float* bih1 = (const float*)d_in[7];
  const float* bhh1 = (const float*)d_in[8];
  const float* Wfc  = (const float*)d_in[9];
  const float* bfc  = (const float*)d_in[10];
  float* out = (float*)d_out;
  char* ws = (char*)d_ws;

  _Float16* P  = (_Float16*)(ws + OFF_P);
  _Float16* B0 = (_Float16*)(ws + OFF_B0);
  _Float16* B1 = (_Float16*)(ws + OFF_B1);
  uint4* R0 = (uint4*)(ws + OFF_R0);
  uint4* L0 = (uint4*)(ws + OFF_L0);
  uint4* R1 = (uint4*)(ws + OFF_R1);
  uint4* L1 = (uint4*)(ws + OFF_L1);
  float* bias0 = (float*)(ws + OFF_BS0);
  float* bias1 = (float*)(ws + OFF_BS1);

  bias_kernel<<<1, 512, 0, stream>>>(bih0, bhh0, bih1, bhh1, bias0, bias1);
  cvt_half_kernel<<<128, 256, 0, stream>>>(Wih0, B0, 512 * 64);
  cvt_half_kernel<<<1024, 256, 0, stream>>>(Wih1, B1, 512 * 512);
  pack_rec_kernel<<<128, 256, 0, stream>>>(Whh0, R0, L0);
  pack_rec_kernel<<<128, 256, 0, stream>>>(Whh1, R1, L1);

  proj_kernel<float, 64><<<2048, 256, 0, stream>>>(x, B0, P, bias0);
  rec_kernel<true, false><<<NB, 256, 0, stream>>>(P, P, R0, L0, nullptr, nullptr, nullptr);
  proj_kernel<_Float16, 512><<<2048, 256, 0, stream>>>(P, B1, P, bias1);
  rec_kernel<false, true><<<NB, 256, 0, stream>>>(P, nullptr, R1, L1, Wfc, bfc, out);
}

// Round 3
// 1876.078 us; speedup vs baseline: 14.7844x; 1.4254x over previous
//
#include <hip/hip_runtime.h>
#include <hip/hip_fp16.h>

// ---------------------------------------------------------------------------
// 2-layer tanh RNN, B=256, T=512, H=512, D=64, + FC(512->1).
//   proj0:  P[b,t,:] = x[b,t,:] @ W_ih0^T + (b_ih0+b_hh0)     (MFMA f16, K=64)
//   rec0:   per-CU recurrence via M=1 MFMA, writes h1 in place over P
//   proj1:  P[b,t,:] = h1[b,t,:] @ W_ih1^T + (b_ih1+b_hh1)    (in-place)
//   rec1:   recurrence + final FC -> d_out[256]
// rec engine: one chain per CU, 256 threads (4 waves, 1 wave/SIMD).
// W_hh as MFMA B-fragments per wave (128 total):
//   64 frags pinned to AGPRs via inline-asm "a" operand constraint (round-2
//   lesson: plain C arrays are NOT fed to MFMA from AGPRs -- the compiler
//   inserted ~750 v_accvgpr-move insts/step, 30% VALUBusy, 2.56us/step),
//   36 frags pinned to VGPRs ("v"), 28 frags in LDS (112 KB, reread/step).
// One barrier per step: per-wave LDS transpose (lanes<16 -> all 64 lanes,
// s_waitcnt lgkmcnt(0) only), tanh on owning threads, double-buffered hbuf.
// ---------------------------------------------------------------------------

typedef _Float16 h2 __attribute__((ext_vector_type(2)));
typedef _Float16 h8 __attribute__((ext_vector_type(8)));
typedef float    f4 __attribute__((ext_vector_type(4)));

#define HID   512
#define TSEQ  512
#define NB    256
#define NREG  100   // B-frags per wave in registers (64 AGPR + 36 VGPR)
#define NAGPR 64
#define NLDS  28    // B-frags per wave in LDS

// per k-step (kk), how many of the 8 n-group frags come from LDS
__host__ __device__ constexpr int nl_of(int kk) { return (kk % 4 == 0) ? 1 : 2; }

// D = A*B + D;  B pinned to AGPR / VGPR respectively.
#define MFMA_A(accv, av, bv) \
  asm("v_mfma_f32_16x16x32_f16 %0, %1, %2, %0" : "+v"(accv) : "v"(av), "a"(bv))
#define MFMA_V(accv, av, bv) \
  asm("v_mfma_f32_16x16x32_f16 %0, %1, %2, %0" : "+v"(accv) : "v"(av), "v"(bv))

// ---------------- workspace layout (bytes) ----------------
static const size_t OFF_P   = 0;                       // [131072][512] fp16  134217728
static const size_t OFF_B0  = 134217728;               // W_ih0 fp16 [512][64]    65536
static const size_t OFF_B1  = OFF_B0 + 65536;          // W_ih1 fp16 [512][512]  524288
static const size_t OFF_R0  = OFF_B1 + 524288;         // BregP layer0 4*100*64*16 = 409600
static const size_t OFF_L0  = OFF_R0 + 409600;         // BldsP layer0 4*28*64*16 = 114688
static const size_t OFF_R1  = OFF_L0 + 114688;
static const size_t OFF_L1  = OFF_R1 + 409600;
static const size_t OFF_BS0 = OFF_L1 + 114688;         // bias0 f32 [512]
static const size_t OFF_BS1 = OFF_BS0 + 2048;          // bias1 f32 [512]

// ---------------- prep kernels ----------------
__global__ void bias_kernel(const float* __restrict__ bih0, const float* __restrict__ bhh0,
                            const float* __restrict__ bih1, const float* __restrict__ bhh1,
                            float* __restrict__ bias0, float* __restrict__ bias1) {
  int i = threadIdx.x;  // block 512
  bias0[i] = bih0[i] + bhh0[i];
  bias1[i] = bih1[i] + bhh1[i];
}

__global__ void cvt_half_kernel(const float* __restrict__ in, _Float16* __restrict__ outp, int n) {
  int i = blockIdx.x * 256 + threadIdx.x;
  if (i < n) outp[i] = (_Float16)in[i];
}

// Pack W_hh (fp32 [512][512]) into MFMA B-fragment order (same map as round 2).
// Fragment for (wave w, n-group g, k-step kk), lane l:
//   8 halfs = W[128w + 16g + (l&15)][kk*32 + (l>>4)*8 .. +8)
__global__ void pack_rec_kernel(const float* __restrict__ W, uint4* __restrict__ BregP,
                                uint4* __restrict__ BldsP) {
  int t = blockIdx.x * 256 + threadIdx.x;   // 32768 threads
  int l  = t & 63;
  int g  = (t >> 6) & 7;
  int kk = (t >> 9) & 15;
  int w  = (t >> 13) & 3;
  int nl = nl_of(kk);
  bool lds = (g >= 8 - nl);
  int slot;
  if (!lds) {
    int R = 0;
    for (int j = 0; j < kk; ++j) R += 8 - nl_of(j);
    slot = R + g;
  } else {
    int L = 0;
    for (int j = 0; j < kk; ++j) L += nl_of(j);
    slot = L + (g - (8 - nl));
  }
  int n  = 128 * w + 16 * g + (l & 15);
  int k0 = kk * 32 + (l >> 4) * 8;
  const float* src = W + (size_t)n * HID + k0;
  h8 v;
#pragma unroll
  for (int i = 0; i < 8; ++i) v[i] = (_Float16)src[i];
  uint4 u = __builtin_bit_cast(uint4, v);
  if (lds) BldsP[(w * NLDS + slot) * 64 + l] = u;
  else     BregP[(w * NREG + slot) * 64 + l] = u;
}

// ---------------- projection GEMM (MFMA f16) ----------------
template <typename AT, int K>
__global__ __launch_bounds__(256, 2) void proj_kernel(const AT* A, const _Float16* __restrict__ Bw,
                                                      _Float16* C, const float* __restrict__ bias) {
  __shared__ _Float16 At[64][40];
  __shared__ _Float16 Bt[512][40];
  const int tid = threadIdx.x;
  const int m0 = blockIdx.x * 64;
  const int wv = tid >> 6;
  const int l = tid & 63;
  const int n0 = wv * 128;
  const int lm = l & 15;
  const int lq = l >> 4;

  f4 acc[4][8];
#pragma unroll
  for (int i = 0; i < 4; ++i)
#pragma unroll
    for (int j = 0; j < 8; ++j) acc[i][j] = (f4){0.f, 0.f, 0.f, 0.f};

  const int arow = tid >> 2;
  const int kq = (tid & 3) * 8;

  for (int k0 = 0; k0 < K; k0 += 32) {
    if (sizeof(AT) == 4) {
      const float* ap = (const float*)A + (size_t)(m0 + arow) * K + k0 + kq;
      h8 v;
#pragma unroll
      for (int i = 0; i < 8; ++i) v[i] = (_Float16)ap[i];
      *(h8*)&At[arow][kq] = v;
    } else {
      *(h8*)&At[arow][kq] = *(const h8*)((const _Float16*)A + (size_t)(m0 + arow) * K + k0 + kq);
    }
#pragma unroll
    for (int rr = 0; rr < 8; ++rr) {
      int rrow = arow + rr * 64;
      *(h8*)&Bt[rrow][kq] = *(const h8*)(Bw + (size_t)rrow * K + k0 + kq);
    }
    __syncthreads();
    h8 af[4];
#pragma unroll
    for (int mm = 0; mm < 4; ++mm) af[mm] = *(const h8*)&At[mm * 16 + lm][lq * 8];
#pragma unroll
    for (int nn = 0; nn < 8; ++nn) {
      h8 bf = *(const h8*)&Bt[n0 + nn * 16 + lm][lq * 8];
#pragma unroll
      for (int mm = 0; mm < 4; ++mm)
        acc[mm][nn] = __builtin_amdgcn_mfma_f32_16x16x32_f16(af[mm], bf, acc[mm][nn], 0, 0, 0);
    }
    __syncthreads();
  }
#pragma unroll
  for (int nn = 0; nn < 8; ++nn) {
    int col = n0 + nn * 16 + lm;
    float bv = bias[col];
#pragma unroll
    for (int mm = 0; mm < 4; ++mm) {
#pragma unroll
      for (int r = 0; r < 4; ++r) {
        int row = m0 + mm * 16 + lq * 4 + r;
        C[(size_t)row * HID + col] = (_Float16)(acc[mm][nn][r] + bv);
      }
    }
  }
}

// ---------------- recurrence kernel (M=1 MFMA, AGPR-pinned weights) ----------------
template <bool WRITE_H, bool DO_FC>
__global__ __launch_bounds__(256, 1) void rec_kernel(
    const _Float16* __restrict__ P, _Float16* __restrict__ Pout,
    const uint4* __restrict__ BregP, const uint4* __restrict__ BldsP,
    const float* __restrict__ Wfc, const float* __restrict__ bfc, float* __restrict__ out) {
  __shared__ __align__(16) uint4 Blds[4 * NLDS * 64];   // 114688 B
  __shared__ __align__(16) _Float16 hbuf[2][HID];       // 2 KB, double-buffered
  __shared__ __align__(16) float hxch[4][128];          // 2 KB, per-wave private
  __shared__ float red[4];
  const int tid = threadIdx.x;
  const int b = blockIdx.x;
  const int w = tid >> 6, l = tid & 63, lq = l >> 4;

  // load register-resident B fragments (one-time). Consumed ONLY as inline-asm
  // "a"/"v" operands, so breg_a lives in AGPRs, breg_v in VGPRs, no per-use moves.
  h8 breg_a[NAGPR];
#pragma unroll
  for (int i = 0; i < NAGPR; ++i)
    breg_a[i] = __builtin_bit_cast(h8, BregP[(w * NREG + i) * 64 + l]);
  h8 breg_v[NREG - NAGPR];
#pragma unroll
  for (int i = 0; i < NREG - NAGPR; ++i)
    breg_v[i] = __builtin_bit_cast(h8, BregP[(w * NREG + NAGPR + i) * 64 + l]);
  // stage LDS-resident fragments
#pragma unroll
  for (int j = 0; j < NLDS; ++j)
    Blds[(w * NLDS + j) * 64 + l] = BldsP[(w * NLDS + j) * 64 + l];

  ((unsigned*)hbuf[0])[tid] = 0u;   // h0 = 0 (buffer 0 only; buffer 1 written before read)
  __syncthreads();

  const _Float16* prow = P + (size_t)b * TSEQ * HID;
  unsigned xp_cur = *(const unsigned*)(prow + 2 * tid);
  float lv0 = 0.f, lv1 = 0.f;

#pragma unroll 1
  for (int t = 0; t < TSEQ; ++t) {
    int tn = (t + 1 < TSEQ) ? t + 1 : t;
    unsigned xp_next = *(const unsigned*)(prow + (size_t)tn * HID + 2 * tid);
    const _Float16* hb = hbuf[t & 1];

    f4 acc[8];
#pragma unroll
    for (int g = 0; g < 8; ++g) acc[g] = (f4){0.f, 0.f, 0.f, 0.f};

    int ri = 0, li = 0;
#pragma unroll
    for (int kk = 0; kk < 16; ++kk) {
      // A-frag: h replicated into all 16 rows (same addr per 16-lane quad -> broadcast)
      h8 a = *(const h8*)(hb + kk * 32 + lq * 8);
      const int nl = nl_of(kk);
#pragma unroll
      for (int g = 0; g < 8; ++g) {
        if (g < 8 - nl) {
          if (ri < NAGPR) { MFMA_A(acc[g], a, breg_a[ri]); }
          else            { MFMA_V(acc[g], a, breg_v[ri - NAGPR]); }
          ++ri;
        } else {
          h8 bf = __builtin_bit_cast(h8, Blds[(w * NLDS + (li++)) * 64 + l]);
          MFMA_V(acc[g], a, bf);
        }
      }
    }

    // per-wave transpose: lanes<16 hold n=128w+16g+l in acc[g][0] (all D rows equal)
    if (l < 16) {
#pragma unroll
      for (int g = 0; g < 8; ++g) hxch[w][16 * g + l] = acc[g][0];
    }
    asm volatile("s_waitcnt lgkmcnt(0)" ::: "memory");   // intra-wave LDS ordering
    float2 hr = *(const float2*)(&hxch[w][2 * l]);       // n = 128w+2l = 2*tid

    h2 xph = __builtin_bit_cast(h2, xp_cur);
    float v0 = tanhf(hr.x + (float)xph[0]);
    float v1 = tanhf(hr.y + (float)xph[1]);
    lv0 = v0; lv1 = v1;
    h2 hw; hw[0] = (_Float16)v0; hw[1] = (_Float16)v1;
    *(h2*)(&hbuf[(t + 1) & 1][2 * tid]) = hw;
    if (WRITE_H)
      *(h2*)(Pout + (size_t)b * TSEQ * HID + (size_t)t * HID + 2 * tid) = hw;
    __syncthreads();   // single barrier per step (hbuf double-buffered)
    xp_cur = xp_next;
  }

  if (DO_FC) {
    float fc = lv0 * Wfc[2 * tid] + lv1 * Wfc[2 * tid + 1];
#pragma unroll
    for (int off = 32; off; off >>= 1) fc += __shfl_down(fc, off, 64);
    if ((tid & 63) == 0) red[tid >> 6] = fc;
    __syncthreads();
    if (tid == 0) out[b] = red[0] + red[1] + red[2] + red[3] + bfc[0];
  }
}

// ---------------- launcher ----------------
extern "C" void kernel_launch(void* const* d_in, const int* in_sizes, int n_in,
                              void* d_out, int out_size, void* d_ws, size_t ws_size,
                              hipStream_t stream) {
  const float* x    = (const float*)d_in[0];
  const float* Wih0 = (const float*)d_in[1];
  const float* Whh0 = (const float*)d_in[2];
  const float* bih0 = (const float*)d_in[3];
  const float* bhh0 = (const float*)d_in[4];
  const float* Wih1 = (const float*)d_in[5];
  const float* Whh1 = (const float*)d_in[6];
  const float* bih1 = (const float*)d_in[7];
  const float* bhh1 = (const float*)d_in[8];
  const float* Wfc  = (const float*)d_in[9];
  const float* bfc  = (const float*)d_in[10];
  float* out = (float*)d_out;
  char* ws = (char*)d_ws;

  _Float16* P  = (_Float16*)(ws + OFF_P);
  _Float16* B0 = (_Float16*)(ws + OFF_B0);
  _Float16* B1 = (_Float16*)(ws + OFF_B1);
  uint4* R0 = (uint4*)(ws + OFF_R0);
  uint4* L0 = (uint4*)(ws + OFF_L0);
  uint4* R1 = (uint4*)(ws + OFF_R1);
  uint4* L1 = (uint4*)(ws + OFF_L1);
  float* bias0 = (float*)(ws + OFF_BS0);
  float* bias1 = (float*)(ws + OFF_BS1);

  bias_kernel<<<1, 512, 0, stream>>>(bih0, bhh0, bih1, bhh1, bias0, bias1);
  cvt_half_kernel<<<128, 256, 0, stream>>>(Wih0, B0, 512 * 64);
  cvt_half_kernel<<<1024, 256, 0, stream>>>(Wih1, B1, 512 * 512);
  pack_rec_kernel<<<128, 256, 0, stream>>>(Whh0, R0, L0);
  pack_rec_kernel<<<128, 256, 0, stream>>>(Whh1, R1, L1);

  proj_kernel<float, 64><<<2048, 256, 0, stream>>>(x, B0, P, bias0);
  rec_kernel<true, false><<<NB, 256, 0, stream>>>(P, P, R0, L0, nullptr, nullptr, nullptr);
  proj_kernel<_Float16, 512><<<2048, 256, 0, stream>>>(P, B1, P, bias1);
  rec_kernel<false, true><<<NB, 256, 0, stream>>>(P, nullptr, R1, L1, Wfc, bfc, out);
}

// Round 4
// 1640.959 us; speedup vs baseline: 16.9027x; 1.1433x over previous
//
#include <hip/hip_runtime.h>
#include <hip/hip_fp16.h>

// ---------------------------------------------------------------------------
// 2-layer tanh RNN, B=256, T=512, H=512, D=64, + FC(512->1).
//   proj0:  P[b,t,:] = x[b,t,:] @ W_ih0^T + (b_ih0+b_hh0)     (MFMA f16, K=64)
//   rec0:   per-CU recurrence via M=1 MFMA, writes h1 in place over P
//   proj1:  P[b,t,:] = h1[b,t,:] @ W_ih1^T + (b_ih1+b_hh1)    (in-place)
//   rec1:   recurrence + final FC -> d_out[256]
//
// rec engine (round 4): one chain per CU, 512 threads = 8 waves = 2 waves/SIMD.
// Round-3 forensics: per-SIMD matrix pipe = ~17-19 cy per 16x16x32 MFMA, so the
// 512 MFMA/CU/step floor is ~2240 cy; at 1 wave/SIMD the ~1900 cy VALU+latency
// tail was exposed (4130 cy/step). 2 waves/SIMD hides the tail under the other
// wave's MFMA issue; pipe time per step is invariant to the wave split.
// Per wave: n-slice 64 = 4 tiles x 16 ksteps = 64 MFMAs/step. Weights per wave:
//   32 frags pinned to AGPRs (asm "a", exactly 128 AGPRs at 2 waves/SIMD),
//   14 frags in VGPRs (56 regs), 18 frags in LDS (147 KB, reread each step --
//   ~1440 cy LDS pipe, parallel to the 2240 cy MFMA pipe).
// One barrier per step; per-wave LDS transpose; double-buffered hbuf.
// ---------------------------------------------------------------------------

typedef _Float16 h2 __attribute__((ext_vector_type(2)));
typedef _Float16 h8 __attribute__((ext_vector_type(8)));
typedef float    f4 __attribute__((ext_vector_type(4)));

#define HID   512
#define TSEQ  512
#define NB    256
#define NWAVE 8
#define NAG   32    // AGPR frags per wave (slots 0..31, interleaved 2 per kstep)
#define NVG   14    // VGPR frags per wave (slots 32..45)
#define NREGF (NAG + NVG)   // 46
#define NLDSF 18    // LDS frags per wave

// D = A*B + D;  B pinned to AGPR / VGPR respectively.
#define MFMA_A(accv, av, bv) \
  asm("v_mfma_f32_16x16x32_f16 %0, %1, %2, %0" : "+v"(accv) : "v"(av), "a"(bv))
#define MFMA_V(accv, av, bv) \
  asm("v_mfma_f32_16x16x32_f16 %0, %1, %2, %0" : "+v"(accv) : "v"(av), "v"(bv))

// ---------------- workspace layout (bytes) ----------------
static const size_t OFF_P   = 0;                       // [131072][512] fp16  134217728
static const size_t OFF_B0  = 134217728;               // W_ih0 fp16 [512][64]    65536
static const size_t OFF_B1  = OFF_B0 + 65536;          // W_ih1 fp16 [512][512]  524288
static const size_t OFF_R0  = OFF_B1 + 524288;         // 8*46*64*16 = 376832
static const size_t OFF_L0  = OFF_R0 + 376832;         // 8*18*64*16 = 147456
static const size_t OFF_R1  = OFF_L0 + 147456;
static const size_t OFF_L1  = OFF_R1 + 376832;
static const size_t OFF_BS0 = OFF_L1 + 147456;         // bias0 f32 [512]
static const size_t OFF_BS1 = OFF_BS0 + 2048;          // bias1 f32 [512]

// ---------------- prep kernels ----------------
__global__ void bias_kernel(const float* __restrict__ bih0, const float* __restrict__ bhh0,
                            const float* __restrict__ bih1, const float* __restrict__ bhh1,
                            float* __restrict__ bias0, float* __restrict__ bias1) {
  int i = threadIdx.x;  // block 512
  bias0[i] = bih0[i] + bhh0[i];
  bias1[i] = bih1[i] + bhh1[i];
}

__global__ void cvt_half_kernel(const float* __restrict__ in, _Float16* __restrict__ outp, int n) {
  int i = blockIdx.x * 256 + threadIdx.x;
  if (i < n) outp[i] = (_Float16)in[i];
}

// Pack W_hh (fp32 [512][512]) into MFMA B-fragment order for the 8-wave rec.
// Fragment (wave w in 0..7, tile g in 0..3, kstep kk in 0..15), lane l:
//   8 halfs = W[64w + 16g + (l&15)][32kk + (l>>4)*8 .. +8)
// Pools: g 0/1 -> reg slot 2kk+g (AGPR); g2 -> kk<14 ? reg 32+kk : lds 16+(kk-14);
//        g3 -> lds kk.
__global__ void pack_rec_kernel(const float* __restrict__ W, uint4* __restrict__ BregP,
                                uint4* __restrict__ BldsP) {
  int t = blockIdx.x * 256 + threadIdx.x;   // 32768 threads
  int l  = t & 63;
  int g  = (t >> 6) & 3;
  int kk = (t >> 8) & 15;
  int w  = (t >> 12) & 7;
  int n  = 64 * w + 16 * g + (l & 15);
  int k0 = 32 * kk + ((l >> 4) & 3) * 8;
  const float* src = W + (size_t)n * HID + k0;
  h8 v;
#pragma unroll
  for (int i = 0; i < 8; ++i) v[i] = (_Float16)src[i];
  uint4 u = __builtin_bit_cast(uint4, v);
  if (g < 2) {
    BregP[(w * NREGF + 2 * kk + g) * 64 + l] = u;
  } else if (g == 2) {
    if (kk < 14) BregP[(w * NREGF + NAG + kk) * 64 + l] = u;
    else         BldsP[(w * NLDSF + 16 + (kk - 14)) * 64 + l] = u;
  } else {
    BldsP[(w * NLDSF + kk) * 64 + l] = u;
  }
}

// ---------------- projection GEMM (MFMA f16) ----------------
template <typename AT, int K>
__global__ __launch_bounds__(256, 2) void proj_kernel(const AT* A, const _Float16* __restrict__ Bw,
                                                      _Float16* C, const float* __restrict__ bias) {
  __shared__ _Float16 At[64][40];
  __shared__ _Float16 Bt[512][40];
  const int tid = threadIdx.x;
  const int m0 = blockIdx.x * 64;
  const int wv = tid >> 6;
  const int l = tid & 63;
  const int n0 = wv * 128;
  const int lm = l & 15;
  const int lq = l >> 4;

  f4 acc[4][8];
#pragma unroll
  for (int i = 0; i < 4; ++i)
#pragma unroll
    for (int j = 0; j < 8; ++j) acc[i][j] = (f4){0.f, 0.f, 0.f, 0.f};

  const int arow = tid >> 2;
  const int kq = (tid & 3) * 8;

  for (int k0 = 0; k0 < K; k0 += 32) {
    if (sizeof(AT) == 4) {
      const float* ap = (const float*)A + (size_t)(m0 + arow) * K + k0 + kq;
      h8 v;
#pragma unroll
      for (int i = 0; i < 8; ++i) v[i] = (_Float16)ap[i];
      *(h8*)&At[arow][kq] = v;
    } else {
      *(h8*)&At[arow][kq] = *(const h8*)((const _Float16*)A + (size_t)(m0 + arow) * K + k0 + kq);
    }
#pragma unroll
    for (int rr = 0; rr < 8; ++rr) {
      int rrow = arow + rr * 64;
      *(h8*)&Bt[rrow][kq] = *(const h8*)(Bw + (size_t)rrow * K + k0 + kq);
    }
    __syncthreads();
    h8 af[4];
#pragma unroll
    for (int mm = 0; mm < 4; ++mm) af[mm] = *(const h8*)&At[mm * 16 + lm][lq * 8];
#pragma unroll
    for (int nn = 0; nn < 8; ++nn) {
      h8 bf = *(const h8*)&Bt[n0 + nn * 16 + lm][lq * 8];
#pragma unroll
      for (int mm = 0; mm < 4; ++mm)
        acc[mm][nn] = __builtin_amdgcn_mfma_f32_16x16x32_f16(af[mm], bf, acc[mm][nn], 0, 0, 0);
    }
    __syncthreads();
  }
#pragma unroll
  for (int nn = 0; nn < 8; ++nn) {
    int col = n0 + nn * 16 + lm;
    float bv = bias[col];
#pragma unroll
    for (int mm = 0; mm < 4; ++mm) {
#pragma unroll
      for (int r = 0; r < 4; ++r) {
        int row = m0 + mm * 16 + lq * 4 + r;
        C[(size_t)row * HID + col] = (_Float16)(acc[mm][nn][r] + bv);
      }
    }
  }
}

// ---------------- recurrence kernel (M=1 MFMA, 8 waves, 2/SIMD) ----------------
template <bool WRITE_H, bool DO_FC>
__global__ __launch_bounds__(512, 2) void rec_kernel(
    const _Float16* __restrict__ P, _Float16* __restrict__ Pout,
    const uint4* __restrict__ BregP, const uint4* __restrict__ BldsP,
    const float* __restrict__ Wfc, const float* __restrict__ bfc, float* __restrict__ out) {
  __shared__ __align__(16) uint4 Blds[NWAVE * NLDSF * 64];  // 147456 B
  __shared__ __align__(16) _Float16 hbuf[2][HID];           // 2 KB, double-buffered
  __shared__ __align__(16) float hxch[NWAVE][64];           // 2 KB, per-wave private
  __shared__ float red[NWAVE];
  const int tid = threadIdx.x;
  const int b = blockIdx.x;
  const int w = tid >> 6, l = tid & 63, lq = l >> 4;

  // one-time loads. breg_a consumed ONLY as asm "a" operands -> AGPRs (128);
  // breg_v as "v" -> VGPRs (56). No per-use moves (round-2 lesson).
  h8 breg_a[NAG];
#pragma unroll
  for (int i = 0; i < NAG; ++i)
    breg_a[i] = __builtin_bit_cast(h8, BregP[(w * NREGF + i) * 64 + l]);
  h8 breg_v[NVG];
#pragma unroll
  for (int i = 0; i < NVG; ++i)
    breg_v[i] = __builtin_bit_cast(h8, BregP[(w * NREGF + NAG + i) * 64 + l]);
#pragma unroll
  for (int j = 0; j < NLDSF; ++j)
    Blds[(w * NLDSF + j) * 64 + l] = BldsP[(w * NLDSF + j) * 64 + l];

  ((unsigned short*)hbuf[0])[tid] = 0;   // h0 = 0 (buffer 1 written before read)
  __syncthreads();

  const _Float16* prow = P + (size_t)b * TSEQ * HID;
  unsigned short xp_cur = *(const unsigned short*)(prow + tid);
  float lv = 0.f;

#pragma unroll 1
  for (int t = 0; t < TSEQ; ++t) {
    int tn = (t + 1 < TSEQ) ? t + 1 : t;
    unsigned short xp_next = *(const unsigned short*)(prow + (size_t)tn * HID + tid);
    const _Float16* hb = hbuf[t & 1];

    f4 acc[4];
#pragma unroll
    for (int g = 0; g < 4; ++g) acc[g] = (f4){0.f, 0.f, 0.f, 0.f};

#pragma unroll
    for (int kk = 0; kk < 16; ++kk) {
      // A-frag: h replicated into 16 rows (quad-uniform address -> broadcast)
      h8 a = *(const h8*)(hb + kk * 32 + lq * 8);
      MFMA_A(acc[0], a, breg_a[2 * kk]);
      MFMA_A(acc[1], a, breg_a[2 * kk + 1]);
      if (kk < 14) {
        MFMA_V(acc[2], a, breg_v[kk]);
      } else {
        h8 bf = __builtin_bit_cast(h8, Blds[(w * NLDSF + 16 + (kk - 14)) * 64 + l]);
        MFMA_V(acc[2], a, bf);
      }
      {
        h8 bf = __builtin_bit_cast(h8, Blds[(w * NLDSF + kk) * 64 + l]);
        MFMA_V(acc[3], a, bf);
      }
    }

    // per-wave transpose: lanes<16 hold n=64w+16g+l in acc[g][0] (all D rows equal)
    if (l < 16) {
#pragma unroll
      for (int g = 0; g < 4; ++g) hxch[w][16 * g + l] = acc[g][0];
    }
    asm volatile("s_waitcnt lgkmcnt(0)" ::: "memory");   // intra-wave LDS ordering
    float hr = hxch[w][l];                               // n = 64w + l = tid

    float v = tanhf(hr + (float)__builtin_bit_cast(_Float16, xp_cur));
    lv = v;
    _Float16 hw = (_Float16)v;
    *(_Float16*)(&hbuf[(t + 1) & 1][tid]) = hw;
    if (WRITE_H)
      *(Pout + (size_t)b * TSEQ * HID + (size_t)t * HID + tid) = hw;
    __syncthreads();   // single barrier per step (hbuf double-buffered)
    xp_cur = xp_next;
  }

  if (DO_FC) {
    float fc = lv * Wfc[tid];
#pragma unroll
    for (int off = 32; off; off >>= 1) fc += __shfl_down(fc, off, 64);
    if (l == 0) red[w] = fc;
    __syncthreads();
    if (tid == 0) {
      float s = bfc[0];
#pragma unroll
      for (int i = 0; i < NWAVE; ++i) s += red[i];
      out[b] = s;
    }
  }
}

// ---------------- launcher ----------------
extern "C" void kernel_launch(void* const* d_in, const int* in_sizes, int n_in,
                              void* d_out, int out_size, void* d_ws, size_t ws_size,
                              hipStream_t stream) {
  const float* x    = (const float*)d_in[0];
  const float* Wih0 = (const float*)d_in[1];
  const float* Whh0 = (const float*)d_in[2];
  const float* bih0 = (const float*)d_in[3];
  const float* bhh0 = (const float*)d_in[4];
  const float* Wih1 = (const float*)d_in[5];
  const float* Whh1 = (const float*)d_in[6];
  const float* bih1 = (const float*)d_in[7];
  const float* bhh1 = (const float*)d_in[8];
  const float* Wfc  = (const float*)d_in[9];
  const float* bfc  = (const float*)d_in[10];
  float* out = (float*)d_out;
  char* ws = (char*)d_ws;

  _Float16* P  = (_Float16*)(ws + OFF_P);
  _Float16* B0 = (_Float16*)(ws + OFF_B0);
  _Float16* B1 = (_Float16*)(ws + OFF_B1);
  uint4* R0 = (uint4*)(ws + OFF_R0);
  uint4* L0 = (uint4*)(ws + OFF_L0);
  uint4* R1 = (uint4*)(ws + OFF_R1);
  uint4* L1 = (uint4*)(ws + OFF_L1);
  float* bias0 = (float*)(ws + OFF_BS0);
  float* bias1 = (float*)(ws + OFF_BS1);

  bias_kernel<<<1, 512, 0, stream>>>(bih0, bhh0, bih1, bhh1, bias0, bias1);
  cvt_half_kernel<<<128, 256, 0, stream>>>(Wih0, B0, 512 * 64);
  cvt_half_kernel<<<1024, 256, 0, stream>>>(Wih1, B1, 512 * 512);
  pack_rec_kernel<<<128, 256, 0, stream>>>(Whh0, R0, L0);
  pack_rec_kernel<<<128, 256, 0, stream>>>(Whh1, R1, L1);

  proj_kernel<float, 64><<<2048, 256, 0, stream>>>(x, B0, P, bias0);
  rec_kernel<true, false><<<NB, 512, 0, stream>>>(P, P, R0, L0, nullptr, nullptr, nullptr);
  proj_kernel<_Float16, 512><<<2048, 256, 0, stream>>>(P, B1, P, bias1);
  rec_kernel<false, true><<<NB, 512, 0, stream>>>(P, nullptr, R1, L1, Wfc, bfc, out);
}